// Round 9
// baseline (232.777 us; speedup 1.0000x reference)
//
#include <hip/hip_runtime.h>
#include <math.h>

#define N_ROWS 400      // bs*Q
#define M_ROWS 80       // = 5*16
#define K_CLS  134
#define PN     12544    // = 392*32
#define PFULL  65536    // 256*256
#define NSUB   25       // 400/16 n-subtiles
#define TSTEPS 392      // PN/32 MFMA k-steps
#define TPB    2        // t-steps per (wave,kc)
#define KCG    49       // kc groups: 4 waves/block, kc = kcg*4+wave

#define CX_BLOCKS 3200  // 400 rows x 8 row-slices (8192 elems each)
#define GY_BLOCKS 245   // 5 j-subtiles x 49 t-chunks

typedef __attribute__((ext_vector_type(4))) float  f32x4;
typedef __attribute__((ext_vector_type(8))) __bf16 bf16x8;

__device__ __forceinline__ float wave_reduce_sum(float v) {
#pragma unroll
    for (int off = 32; off > 0; off >>= 1) v += __shfl_down(v, off, 64);
    return v;
}

// --- block 0: bitmap sort -> sel (ascending), global bitmap bitsG,
//     prefix counts kbase[64] (selected count before element i*1024).
//     blocks 1..25: softmax stats (16 rows each, one per wave). ---
__global__ __launch_bounds__(1024) void sort_softmax_kernel(
        const int* __restrict__ point_idx, int* __restrict__ sel,
        unsigned int* __restrict__ bitsG, int* __restrict__ kbase,
        const float* __restrict__ pred_logits,
        float* __restrict__ rowmax, float* __restrict__ rowsum) {
    int tid = threadIdx.x;
    if (blockIdx.x == 0) {
        __shared__ unsigned int bits[PFULL / 32];   // 8 KB
        __shared__ int wtot[16], wbase[16];
        bits[tid] = 0u; bits[tid + 1024] = 0u;
        __syncthreads();
        for (int i = tid; i < PN; i += 1024) {
            int p = point_idx[i];
            atomicOr(&bits[p >> 5], 1u << (p & 31));
        }
        __syncthreads();
        bitsG[tid] = bits[tid]; bitsG[tid + 1024] = bits[tid + 1024];
        unsigned int w0 = bits[tid * 2], w1 = bits[tid * 2 + 1];
        int cnt = __popc(w0) + __popc(w1);
        int lane = tid & 63, wid = tid >> 6;
        int v = cnt;
#pragma unroll
        for (int off = 1; off < 64; off <<= 1) {
            int u = __shfl_up(v, off, 64);
            if (lane >= off) v += u;
        }
        if (lane == 63) wtot[wid] = v;
        __syncthreads();
        if (tid == 0) {
            int run = 0;
#pragma unroll
            for (int i = 0; i < 16; ++i) { wbase[i] = run; run += wtot[i]; }
        }
        __syncthreads();
        int base = wbase[wid] + (v - cnt);          // exclusive prefix
        if ((tid & 15) == 0) kbase[tid >> 4] = base; // element tid*64 = (tid>>4)*1024
        int p0 = tid * 64;
        while (w0) { int b = __builtin_ctz(w0); w0 &= w0 - 1; sel[base++] = p0 + b; }
        p0 += 32;
        while (w1) { int b = __builtin_ctz(w1); w1 &= w1 - 1; sel[base++] = p0 + b; }
    } else {
        // softmax stats: one row per wave, 16 waves/block
        int wave = tid >> 6, lane = tid & 63;
        int n = (blockIdx.x - 1) * 16 + wave;       // < 400
        const float* row = pred_logits + n * K_CLS;
        float mx = -1e30f;
        for (int k = lane; k < K_CLS; k += 64) mx = fmaxf(mx, row[k]);
#pragma unroll
        for (int off = 32; off > 0; off >>= 1) mx = fmaxf(mx, __shfl_down(mx, off, 64));
        mx = __shfl(mx, 0, 64);
        float se = 0.f;
        for (int k = lane; k < K_CLS; k += 64) se += expf(row[k] - mx);
        se = wave_reduce_sum(se);
        if (lane == 0) { rowmax[n] = mx; rowsum[n] = se; }
    }
}

// --- stage2: blocks [0,3200): stream-compact pred_masks -> packed bf16 Xb.
//     Coalesced full-row streaming; ballot-rank compaction (NO scalar gathers).
//     blocks [3200,3445): gather y into B-fragment layout + ypart. ---
__global__ __launch_bounds__(256) void stage2_kernel(
        const float* __restrict__ pred_masks, const float* __restrict__ tgt_masks,
        const int* __restrict__ sel, const unsigned int* __restrict__ bitsG,
        const int* __restrict__ kbase,
        __bf16* __restrict__ Xb, __bf16* __restrict__ Yb, float* __restrict__ ypart) {
    __shared__ float smem[64];
    int b = blockIdx.x;
    int wave = threadIdx.x >> 6, lane = threadIdx.x & 63;
    if (b < CX_BLOCKS) {
        // ---- compact x: row r, slice i8 (8192 elems); wave owns 2048 ----
        int r = b >> 3, i8 = b & 7;
        const float* row = pred_masks + (size_t)r * PFULL;
        __bf16* xr = Xb + (size_t)r * PN;
        int e = i8 * 8192 + wave * 2048;
        int base = kbase[e >> 10];
        unsigned long long below = (1ULL << lane) - 1;
#pragma unroll
        for (int win = 0; win < 8; ++win) {
            int e0 = e + win * 256;
            float xv[4]; unsigned int wrd[4];
#pragma unroll
            for (int j = 0; j < 4; ++j) {
                int ei = e0 + j * 64 + lane;
                xv[j]  = row[ei];
                wrd[j] = bitsG[ei >> 5];
            }
#pragma unroll
            for (int j = 0; j < 4; ++j) {
                int bit = (wrd[j] >> (lane & 31)) & 1;
                unsigned long long bal = __ballot(bit);
                if (bit) {
                    int rank = __popcll(bal & below);
                    xr[base + rank] = (__bf16)xv[j];
                }
                base += __popcll(bal);
            }
        }
    } else {
        // ---- gather y: frag (t,j), lane l holds
        //      B[k=t*32+(l>>4)*8+jj][m=16*j+(l&15)]; 2 t per wave ----
        int bb = b - CX_BLOCKS;
        int j = bb / 49, tch = bb % 49;
        int colL = lane & 15, quad = lane >> 4;
        int m = 16 * j + colL;
        const float* yrow = tgt_masks + (size_t)m * PFULL;
        float acc = 0.f;
#pragma unroll
        for (int u = 0; u < 2; ++u) {
            int t = tch * 8 + wave * 2 + u;
            int k0 = t * 32 + quad * 8;
            int idx[8];
            *(int4*)(idx)     = *(const int4*)(sel + k0);
            *(int4*)(idx + 4) = *(const int4*)(sel + k0 + 4);
            bf16x8 v;
#pragma unroll
            for (int jj = 0; jj < 8; ++jj) {
                float y = yrow[idx[jj]];
                v[jj] = (__bf16)y;
                acc += y;
            }
            ((bf16x8*)Yb)[(size_t)(t * 5 + j) * 64 + lane] = v;
        }
        acc += __shfl_down(acc, 32, 64);
        acc += __shfl_down(acc, 16, 64);
        if (quad == 0) smem[wave * 16 + colL] = acc;
        __syncthreads();
        if (threadIdx.x < 16) {
            float s = smem[threadIdx.x] + smem[16 + threadIdx.x] +
                      smem[32 + threadIdx.x] + smem[48 + threadIdx.x];
            ypart[tch * M_ROWS + 16 * j + threadIdx.x] = s;
        }
    }
}

// --- GEMM from packed Xb (coalesced) + Yb frags. sigmoid/softplus computed
//     dense in-register. ZERO atomics: 4-wave LDS reduce + partial writes. ---
__global__ __launch_bounds__(256) void gemm_kernel(
        const __bf16* __restrict__ Xb, const __bf16* __restrict__ Yb,
        float* __restrict__ xypart, float* __restrict__ sypart,
        float* __restrict__ rowS, float* __restrict__ rowSP) {
    __shared__ float red[4][40][64];       // 40 KB, lane-major: conflict-free
    __shared__ float rowred[4][2][16];
    int wave = threadIdx.x >> 6, lane = threadIdx.x & 63;
    int nsub = blockIdx.x / KCG, kcg = blockIdx.x % KCG;
    int kc = kcg * 4 + wave;
    int n0 = nsub * 16;
    int colL = lane & 15, quad = lane >> 4;
    int tbase = kc * TPB;

    const __bf16* xrow = Xb + (size_t)(n0 + colL) * PN;   // A[m=lane&15]
    const bf16x8* Yfrag = (const bf16x8*)Yb;

    f32x4 accX[5], accS[5];
    f32x4 zero = {0.f, 0.f, 0.f, 0.f};
#pragma unroll
    for (int j = 0; j < 5; ++j) { accX[j] = zero; accS[j] = zero; }
    float sumS = 0.f, sumSP = 0.f;

    bf16x8 Av[TPB], Bbuf[TPB][5];
#pragma unroll
    for (int i = 0; i < TPB; ++i) {        // all loads upfront, coalesced
        int t = tbase + i;
        Av[i] = *(const bf16x8*)(xrow + (size_t)t * 32 + quad * 8);
        const bf16x8* q = Yfrag + (size_t)(t * 5) * 64 + lane;
#pragma unroll
        for (int j = 0; j < 5; ++j) Bbuf[i][j] = q[(size_t)j * 64];
    }
#pragma unroll
    for (int i = 0; i < TPB; ++i) {
        bf16x8 aS;
#pragma unroll
        for (int jj = 0; jj < 8; ++jj) {
            float x  = (float)Av[i][jj];
            float ax = fabsf(x);
            float e  = __expf(-ax);
            float inv = __builtin_amdgcn_rcpf(1.f + e);
            float sig = (x >= 0.f) ? inv : e * inv;
            float sp  = fmaxf(x, 0.f) + __logf(1.f + e);
            aS[jj] = (__bf16)sig;
            sumS += sig; sumSP += sp;
        }
#pragma unroll
        for (int j = 0; j < 5; ++j) {
            accX[j] = __builtin_amdgcn_mfma_f32_16x16x32_bf16(Av[i], Bbuf[i][j], accX[j], 0, 0, 0);
            accS[j] = __builtin_amdgcn_mfma_f32_16x16x32_bf16(aS,    Bbuf[i][j], accS[j], 0, 0, 0);
        }
    }

    // ---- stash accumulators in LDS ----
#pragma unroll
    for (int j = 0; j < 5; ++j)
#pragma unroll
        for (int r = 0; r < 4; ++r) {
            red[wave][j * 4 + r][lane]      = accX[j][r];
            red[wave][20 + j * 4 + r][lane] = accS[j][r];
        }
    sumS  += __shfl_down(sumS, 32, 64);
    sumS  += __shfl_down(sumS, 16, 64);
    sumSP += __shfl_down(sumSP, 32, 64);
    sumSP += __shfl_down(sumSP, 16, 64);
    if (lane < 16) { rowred[wave][0][lane] = sumS; rowred[wave][1][lane] = sumSP; }
    __syncthreads();
    // ---- each wave reduces a 10-value slice across 4 waves, writes partials ----
#pragma unroll
    for (int v0 = 0; v0 < 10; ++v0) {
        int v = wave * 10 + v0;
        float s = red[0][v][lane] + red[1][v][lane] + red[2][v][lane] + red[3][v][lane];
        int vv = (v < 20) ? v : v - 20;
        int j = vv >> 2, r = vv & 3;
        int n = n0 + quad * 4 + r, m = 16 * j + colL;   // verified C/D layout
        float* dst = (v < 20) ? xypart : sypart;
        dst[(size_t)kcg * (N_ROWS * M_ROWS) + n * M_ROWS + m] = s;
    }
    if (threadIdx.x < 16) {
        rowS[kcg * N_ROWS + n0 + threadIdx.x] =
            rowred[0][0][threadIdx.x] + rowred[1][0][threadIdx.x] +
            rowred[2][0][threadIdx.x] + rowred[3][0][threadIdx.x];
    } else if (threadIdx.x < 32) {
        int l = threadIdx.x - 16;
        rowSP[kcg * N_ROWS + n0 + l] =
            rowred[0][1][l] + rowred[1][1][l] + rowred[2][1][l] + rowred[3][1][l];
    }
}

// --- combine: reduce partials (49 groups) + all cost terms ---
__global__ void combine_kernel(const float* __restrict__ logits,
                               const int* __restrict__ tgt_labels,
                               const float* __restrict__ rowmax,
                               const float* __restrict__ rowsum,
                               const float* __restrict__ rowS,
                               const float* __restrict__ rowSP,
                               const float* __restrict__ ypart,
                               const float* __restrict__ xypart,
                               const float* __restrict__ sypart,
                               float* __restrict__ out) {
    int idx = blockIdx.x * blockDim.x + threadIdx.x;
    if (idx >= N_ROWS * M_ROWS) return;
    int n = idx / M_ROWS, m = idx % M_ROWS;
    float xy = 0.f, sy = 0.f, ssumv = 0.f, spsumv = 0.f, ysum = 0.f;
#pragma unroll 7
    for (int g = 0; g < KCG; ++g) {
        xy += xypart[(size_t)g * (N_ROWS * M_ROWS) + idx];
        sy += sypart[(size_t)g * (N_ROWS * M_ROWS) + idx];
        ssumv  += rowS[g * N_ROWS + n];
        spsumv += rowSP[g * N_ROWS + n];
        ysum += ypart[g * M_ROWS + m];
    }
    int tid = tgt_labels[m];
    tid = min(max(tid, 0), K_CLS - 1);
    float p = expf(logits[n * K_CLS + tid] - rowmax[n]) / rowsum[n];
    float cost_class = -p;
    float cost_mask = (spsumv - xy) * (1.0f / PN);
    float cost_dice = 1.f - (2.f * sy + 1.f) / (ssumv + ysum + 1.f);
    out[idx] = 2.f * cost_class + 5.f * cost_mask + 5.f * cost_dice;
}

extern "C" void kernel_launch(void* const* d_in, const int* in_sizes, int n_in,
                              void* d_out, int out_size, void* d_ws, size_t ws_size,
                              hipStream_t stream) {
    const float* pred_logits = (const float*)d_in[0];   // (4,100,134)
    const float* pred_masks  = (const float*)d_in[1];   // (4,100,256,256)
    const int*   tgt_labels  = (const int*)d_in[2];     // (80,)
    const float* tgt_masks   = (const float*)d_in[3];   // (80,256,256)
    const int*   point_idx   = (const int*)d_in[4];     // (12544,)
    float* out = (float*)d_out;                         // (4,100,80)

    char* ws = (char*)d_ws;
    size_t off = 0;
    auto carve = [&](size_t nbytes) {
        char* p = ws + off;
        off += (nbytes + 255) & ~(size_t)255;
        return p;
    };
    // all buffers fully overwritten every launch -> NO zero-init anywhere
    int*      sel    = (int*)carve(PN * 4);
    unsigned* bitsG  = (unsigned*)carve((PFULL / 32) * 4);
    int*      kbase  = (int*)carve(64 * 4);
    float*    rowmax = (float*)carve(N_ROWS * 4);
    float*    rowsum = (float*)carve(N_ROWS * 4);
    float*    ypart  = (float*)carve(KCG * M_ROWS * 4);
    float*    rowS   = (float*)carve(KCG * N_ROWS * 4);
    float*    rowSP  = (float*)carve(KCG * N_ROWS * 4);
    float*    xypart = (float*)carve((size_t)KCG * N_ROWS * M_ROWS * 4);  // 6.27 MB
    float*    sypart = (float*)carve((size_t)KCG * N_ROWS * M_ROWS * 4);  // 6.27 MB
    __bf16*   Xb     = (__bf16*)carve((size_t)N_ROWS * PN * 2);           // 10.04 MB
    __bf16*   Yb     = (__bf16*)carve((size_t)TSTEPS * 5 * 1024);         //  2.01 MB
    (void)ws_size; (void)in_sizes; (void)n_in; (void)out_size;

    sort_softmax_kernel<<<26, 1024, 0, stream>>>(
        point_idx, sel, bitsG, kbase, pred_logits, rowmax, rowsum);
    stage2_kernel<<<CX_BLOCKS + GY_BLOCKS, 256, 0, stream>>>(
        pred_masks, tgt_masks, sel, bitsG, kbase, Xb, Yb, ypart);
    gemm_kernel<<<NSUB * KCG, 256, 0, stream>>>(
        Xb, Yb, xypart, sypart, rowS, rowSP);
    combine_kernel<<<(N_ROWS * M_ROWS + 255) / 256, 256, 0, stream>>>(
        pred_logits, tgt_labels, rowmax, rowsum, rowS, rowSP, ypart, xypart, sypart, out);
}

// Round 10
// 223.364 us; speedup vs baseline: 1.0421x; 1.0421x over previous
//
#include <hip/hip_runtime.h>
#include <math.h>

#define N_ROWS 400      // bs*Q
#define M_ROWS 80       // = 5*16
#define K_CLS  134
#define PN     12544    // = 392*32
#define PFULL  65536    // 256*256
#define NSUB   25       // 400/16 n-subtiles
#define TSTEPS 392      // PN/32 MFMA k-steps
#define TPB    2        // t-steps per (wave,kc)
#define KCG    49       // kc groups: 4 waves/block, kc = kcg*4+wave

#define CX_BLOCKS 3200  // 400 rows x 8 block-slices (4 wave-slices of 2048 each)
#define GY_BLOCKS 245   // 5 j-subtiles x 49 t-chunks

typedef __attribute__((ext_vector_type(4))) float  f32x4;
typedef __attribute__((ext_vector_type(8))) __bf16 bf16x8;

__device__ __forceinline__ float wave_reduce_sum(float v) {
#pragma unroll
    for (int off = 32; off > 0; off >>= 1) v += __shfl_down(v, off, 64);
    return v;
}

// --- block 0: bitmap sort -> sel (ascending), global bitmap bitsG,
//     prefix counts pbase[256] (selected count before element w*256).
//     blocks 1..25: softmax stats (16 rows each, one per wave). ---
__global__ __launch_bounds__(1024) void sort_softmax_kernel(
        const int* __restrict__ point_idx, int* __restrict__ sel,
        unsigned int* __restrict__ bitsG, int* __restrict__ pbase,
        const float* __restrict__ pred_logits,
        float* __restrict__ rowmax, float* __restrict__ rowsum) {
    int tid = threadIdx.x;
    if (blockIdx.x == 0) {
        __shared__ unsigned int bits[PFULL / 32];   // 8 KB
        __shared__ int wtot[16], wbase[16];
        bits[tid] = 0u; bits[tid + 1024] = 0u;
        __syncthreads();
        for (int i = tid; i < PN; i += 1024) {
            int p = point_idx[i];
            atomicOr(&bits[p >> 5], 1u << (p & 31));
        }
        __syncthreads();
        bitsG[tid] = bits[tid]; bitsG[tid + 1024] = bits[tid + 1024];
        unsigned int w0 = bits[tid * 2], w1 = bits[tid * 2 + 1];
        int cnt = __popc(w0) + __popc(w1);
        int lane = tid & 63, wid = tid >> 6;
        int v = cnt;
#pragma unroll
        for (int off = 1; off < 64; off <<= 1) {
            int u = __shfl_up(v, off, 64);
            if (lane >= off) v += u;
        }
        if (lane == 63) wtot[wid] = v;
        __syncthreads();
        if (tid == 0) {
            int run = 0;
#pragma unroll
            for (int i = 0; i < 16; ++i) { wbase[i] = run; run += wtot[i]; }
        }
        __syncthreads();
        int base = wbase[wid] + (v - cnt);          // exclusive prefix
        // element tid*64 boundary: window (tid*64)/256 = tid>>2
        if ((tid & 3) == 0) pbase[tid >> 2] = base;
        int p0 = tid * 64;
        while (w0) { int b = __builtin_ctz(w0); w0 &= w0 - 1; sel[base++] = p0 + b; }
        p0 += 32;
        while (w1) { int b = __builtin_ctz(w1); w1 &= w1 - 1; sel[base++] = p0 + b; }
    } else {
        // softmax stats: one row per wave, 16 waves/block
        int wave = tid >> 6, lane = tid & 63;
        int n = (blockIdx.x - 1) * 16 + wave;       // < 400
        const float* row = pred_logits + n * K_CLS;
        float mx = -1e30f;
        for (int k = lane; k < K_CLS; k += 64) mx = fmaxf(mx, row[k]);
#pragma unroll
        for (int off = 32; off > 0; off >>= 1) mx = fmaxf(mx, __shfl_down(mx, off, 64));
        mx = __shfl(mx, 0, 64);
        float se = 0.f;
        for (int k = lane; k < K_CLS; k += 64) se += expf(row[k] - mx);
        se = wave_reduce_sum(se);
        if (lane == 0) { rowmax[n] = mx; rowsum[n] = se; }
    }
}

// --- stage2: blocks [0,3200): stream-compact pred_masks -> packed bf16 Xb.
//     Per wave: 2048-elem slice. 8 float4 loads ALL in flight; 1 bitmap word
//     per lane; per-window base from pbase (no serial chain); rank via wave
//     prefix-sum. blocks [3200,3445): gather y into B-frag layout + ypart. ---
__global__ __launch_bounds__(256) void stage2_kernel(
        const float* __restrict__ pred_masks, const float* __restrict__ tgt_masks,
        const int* __restrict__ sel, const unsigned int* __restrict__ bitsG,
        const int* __restrict__ pbase,
        __bf16* __restrict__ Xb, __bf16* __restrict__ Yb, float* __restrict__ ypart) {
    __shared__ float smem[64];
    int b = blockIdx.x;
    int wave = threadIdx.x >> 6, lane = threadIdx.x & 63;
    if (b < CX_BLOCKS) {
        // ---- compact x: row r, wave-slice s (2048 elems) ----
        int r = b >> 3;
        int s = (b & 7) * 4 + wave;                 // 0..31
        int e = s * 2048;
        const float* row = pred_masks + (size_t)r * PFULL;
        __bf16* xr = Xb + (size_t)r * PN;

        // all loads up-front: 8 x float4 (32 VGPRs of data) + 1 bitmap word
        const f32x4* rp = (const f32x4*)(row + e);
        f32x4 xv[8];
#pragma unroll
        for (int i = 0; i < 8; ++i) xv[i] = rp[(size_t)i * 64 + lane];
        unsigned int wrd = bitsG[(e >> 5) + lane];  // bits for elems [e+32*lane, +32)
        int wb[8];
#pragma unroll
        for (int i = 0; i < 8; ++i) wb[i] = pbase[(e >> 8) + i];   // uniform

#pragma unroll
        for (int i = 0; i < 8; ++i) {
            // lane's 4 elements: e + 256*i + 4*lane .. +4
            int srcw = 8 * i + (lane >> 3);
            unsigned int nib = (__shfl(wrd, srcw, 64) >> (4 * (lane & 7))) & 0xFu;
            int c = __popc(nib);
            int pfx = c;
#pragma unroll
            for (int off = 1; off < 64; off <<= 1) {
                int u = __shfl_up(pfx, off, 64);
                if (lane >= off) pfx += u;
            }
            __bf16* dst = xr + wb[i] + (pfx - c);   // exclusive prefix rank
            __bf16 v0 = (__bf16)xv[i][0], v1 = (__bf16)xv[i][1];
            __bf16 v2 = (__bf16)xv[i][2], v3 = (__bf16)xv[i][3];
            int o = 0;
            if (nib & 1u) { dst[o] = v0; ++o; }
            if (nib & 2u) { dst[o] = v1; ++o; }
            if (nib & 4u) { dst[o] = v2; ++o; }
            if (nib & 8u) { dst[o] = v3; }
        }
    } else {
        // ---- gather y: frag (t,j), lane l holds
        //      B[k=t*32+(l>>4)*8+jj][m=16*j+(l&15)]; 2 t per wave ----
        int bb = b - CX_BLOCKS;
        int j = bb / 49, tch = bb % 49;
        int colL = lane & 15, quad = lane >> 4;
        int m = 16 * j + colL;
        const float* yrow = tgt_masks + (size_t)m * PFULL;
        float acc = 0.f;
#pragma unroll
        for (int u = 0; u < 2; ++u) {
            int t = tch * 8 + wave * 2 + u;
            int k0 = t * 32 + quad * 8;
            int idx[8];
            *(int4*)(idx)     = *(const int4*)(sel + k0);
            *(int4*)(idx + 4) = *(const int4*)(sel + k0 + 4);
            bf16x8 v;
#pragma unroll
            for (int jj = 0; jj < 8; ++jj) {
                float y = yrow[idx[jj]];
                v[jj] = (__bf16)y;
                acc += y;
            }
            ((bf16x8*)Yb)[(size_t)(t * 5 + j) * 64 + lane] = v;
        }
        acc += __shfl_down(acc, 32, 64);
        acc += __shfl_down(acc, 16, 64);
        if (quad == 0) smem[wave * 16 + colL] = acc;
        __syncthreads();
        if (threadIdx.x < 16) {
            float s = smem[threadIdx.x] + smem[16 + threadIdx.x] +
                      smem[32 + threadIdx.x] + smem[48 + threadIdx.x];
            ypart[tch * M_ROWS + 16 * j + threadIdx.x] = s;
        }
    }
}

// --- GEMM from packed Xb (coalesced) + Yb frags. sigmoid/softplus computed
//     dense in-register. ZERO atomics: 4-wave LDS reduce + partial writes. ---
__global__ __launch_bounds__(256) void gemm_kernel(
        const __bf16* __restrict__ Xb, const __bf16* __restrict__ Yb,
        float* __restrict__ xypart, float* __restrict__ sypart,
        float* __restrict__ rowS, float* __restrict__ rowSP) {
    __shared__ float red[4][40][64];       // 40 KB, lane-major: conflict-free
    __shared__ float rowred[4][2][16];
    int wave = threadIdx.x >> 6, lane = threadIdx.x & 63;
    int nsub = blockIdx.x / KCG, kcg = blockIdx.x % KCG;
    int kc = kcg * 4 + wave;
    int n0 = nsub * 16;
    int colL = lane & 15, quad = lane >> 4;
    int tbase = kc * TPB;

    const __bf16* xrow = Xb + (size_t)(n0 + colL) * PN;   // A[m=lane&15]
    const bf16x8* Yfrag = (const bf16x8*)Yb;

    f32x4 accX[5], accS[5];
    f32x4 zero = {0.f, 0.f, 0.f, 0.f};
#pragma unroll
    for (int j = 0; j < 5; ++j) { accX[j] = zero; accS[j] = zero; }
    float sumS = 0.f, sumSP = 0.f;

    bf16x8 Av[TPB], Bbuf[TPB][5];
#pragma unroll
    for (int i = 0; i < TPB; ++i) {        // all loads upfront, coalesced
        int t = tbase + i;
        Av[i] = *(const bf16x8*)(xrow + (size_t)t * 32 + quad * 8);
        const bf16x8* q = Yfrag + (size_t)(t * 5) * 64 + lane;
#pragma unroll
        for (int j = 0; j < 5; ++j) Bbuf[i][j] = q[(size_t)j * 64];
    }
#pragma unroll
    for (int i = 0; i < TPB; ++i) {
        bf16x8 aS;
#pragma unroll
        for (int jj = 0; jj < 8; ++jj) {
            float x  = (float)Av[i][jj];
            float ax = fabsf(x);
            float e  = __expf(-ax);
            float inv = __builtin_amdgcn_rcpf(1.f + e);
            float sig = (x >= 0.f) ? inv : e * inv;
            float sp  = fmaxf(x, 0.f) + __logf(1.f + e);
            aS[jj] = (__bf16)sig;
            sumS += sig; sumSP += sp;
        }
#pragma unroll
        for (int j = 0; j < 5; ++j) {
            accX[j] = __builtin_amdgcn_mfma_f32_16x16x32_bf16(Av[i], Bbuf[i][j], accX[j], 0, 0, 0);
            accS[j] = __builtin_amdgcn_mfma_f32_16x16x32_bf16(aS,    Bbuf[i][j], accS[j], 0, 0, 0);
        }
    }

    // ---- stash accumulators in LDS ----
#pragma unroll
    for (int j = 0; j < 5; ++j)
#pragma unroll
        for (int r = 0; r < 4; ++r) {
            red[wave][j * 4 + r][lane]      = accX[j][r];
            red[wave][20 + j * 4 + r][lane] = accS[j][r];
        }
    sumS  += __shfl_down(sumS, 32, 64);
    sumS  += __shfl_down(sumS, 16, 64);
    sumSP += __shfl_down(sumSP, 32, 64);
    sumSP += __shfl_down(sumSP, 16, 64);
    if (lane < 16) { rowred[wave][0][lane] = sumS; rowred[wave][1][lane] = sumSP; }
    __syncthreads();
    // ---- each wave reduces a 10-value slice across 4 waves, writes partials ----
#pragma unroll
    for (int v0 = 0; v0 < 10; ++v0) {
        int v = wave * 10 + v0;
        float s = red[0][v][lane] + red[1][v][lane] + red[2][v][lane] + red[3][v][lane];
        int vv = (v < 20) ? v : v - 20;
        int j = vv >> 2, r = vv & 3;
        int n = n0 + quad * 4 + r, m = 16 * j + colL;   // verified C/D layout
        float* dst = (v < 20) ? xypart : sypart;
        dst[(size_t)kcg * (N_ROWS * M_ROWS) + n * M_ROWS + m] = s;
    }
    if (threadIdx.x < 16) {
        rowS[kcg * N_ROWS + n0 + threadIdx.x] =
            rowred[0][0][threadIdx.x] + rowred[1][0][threadIdx.x] +
            rowred[2][0][threadIdx.x] + rowred[3][0][threadIdx.x];
    } else if (threadIdx.x < 32) {
        int l = threadIdx.x - 16;
        rowSP[kcg * N_ROWS + n0 + l] =
            rowred[0][1][l] + rowred[1][1][l] + rowred[2][1][l] + rowred[3][1][l];
    }
}

// --- combine: reduce partials (49 groups) + all cost terms ---
__global__ void combine_kernel(const float* __restrict__ logits,
                               const int* __restrict__ tgt_labels,
                               const float* __restrict__ rowmax,
                               const float* __restrict__ rowsum,
                               const float* __restrict__ rowS,
                               const float* __restrict__ rowSP,
                               const float* __restrict__ ypart,
                               const float* __restrict__ xypart,
                               const float* __restrict__ sypart,
                               float* __restrict__ out) {
    int idx = blockIdx.x * blockDim.x + threadIdx.x;
    if (idx >= N_ROWS * M_ROWS) return;
    int n = idx / M_ROWS, m = idx % M_ROWS;
    float xy = 0.f, sy = 0.f, ssumv = 0.f, spsumv = 0.f, ysum = 0.f;
#pragma unroll 7
    for (int g = 0; g < KCG; ++g) {
        xy += xypart[(size_t)g * (N_ROWS * M_ROWS) + idx];
        sy += sypart[(size_t)g * (N_ROWS * M_ROWS) + idx];
        ssumv  += rowS[g * N_ROWS + n];
        spsumv += rowSP[g * N_ROWS + n];
        ysum += ypart[g * M_ROWS + m];
    }
    int tid = tgt_labels[m];
    tid = min(max(tid, 0), K_CLS - 1);
    float p = expf(logits[n * K_CLS + tid] - rowmax[n]) / rowsum[n];
    float cost_class = -p;
    float cost_mask = (spsumv - xy) * (1.0f / PN);
    float cost_dice = 1.f - (2.f * sy + 1.f) / (ssumv + ysum + 1.f);
    out[idx] = 2.f * cost_class + 5.f * cost_mask + 5.f * cost_dice;
}

extern "C" void kernel_launch(void* const* d_in, const int* in_sizes, int n_in,
                              void* d_out, int out_size, void* d_ws, size_t ws_size,
                              hipStream_t stream) {
    const float* pred_logits = (const float*)d_in[0];   // (4,100,134)
    const float* pred_masks  = (const float*)d_in[1];   // (4,100,256,256)
    const int*   tgt_labels  = (const int*)d_in[2];     // (80,)
    const float* tgt_masks   = (const float*)d_in[3];   // (80,256,256)
    const int*   point_idx   = (const int*)d_in[4];     // (12544,)
    float* out = (float*)d_out;                         // (4,100,80)

    char* ws = (char*)d_ws;
    size_t off = 0;
    auto carve = [&](size_t nbytes) {
        char* p = ws + off;
        off += (nbytes + 255) & ~(size_t)255;
        return p;
    };
    // all buffers fully overwritten every launch -> NO zero-init anywhere
    int*      sel    = (int*)carve(PN * 4);
    unsigned* bitsG  = (unsigned*)carve((PFULL / 32) * 4);
    int*      pbase  = (int*)carve(256 * 4);
    float*    rowmax = (float*)carve(N_ROWS * 4);
    float*    rowsum = (float*)carve(N_ROWS * 4);
    float*    ypart  = (float*)carve(KCG * M_ROWS * 4);
    float*    rowS   = (float*)carve(KCG * N_ROWS * 4);
    float*    rowSP  = (float*)carve(KCG * N_ROWS * 4);
    float*    xypart = (float*)carve((size_t)KCG * N_ROWS * M_ROWS * 4);  // 6.27 MB
    float*    sypart = (float*)carve((size_t)KCG * N_ROWS * M_ROWS * 4);  // 6.27 MB
    __bf16*   Xb     = (__bf16*)carve((size_t)N_ROWS * PN * 2);           // 10.04 MB
    __bf16*   Yb     = (__bf16*)carve((size_t)TSTEPS * 5 * 1024);         //  2.01 MB
    (void)ws_size; (void)in_sizes; (void)n_in; (void)out_size;

    sort_softmax_kernel<<<26, 1024, 0, stream>>>(
        point_idx, sel, bitsG, pbase, pred_logits, rowmax, rowsum);
    stage2_kernel<<<CX_BLOCKS + GY_BLOCKS, 256, 0, stream>>>(
        pred_masks, tgt_masks, sel, bitsG, pbase, Xb, Yb, ypart);
    gemm_kernel<<<NSUB * KCG, 256, 0, stream>>>(
        Xb, Yb, xypart, sypart, rowS, rowSP);
    combine_kernel<<<(N_ROWS * M_ROWS + 255) / 256, 256, 0, stream>>>(
        pred_logits, tgt_labels, rowmax, rowsum, rowS, rowSP, ypart, xypart, sypart, out);
}